// Round 1
// baseline (1365.807 us; speedup 1.0000x reference)
//
#include <hip/hip_runtime.h>
#include <math.h>

#define BB 8
#define NN 512
#define CC 768
#define HH 12
#define HD 64
#define TOPK 90
#define QKV_ELEMS (BB*HH*NN*HD)   // 3145728 elements per q/k/v tensor

// ---------------------------------------------------------------------------
// Kernel 1: QKV GEMM.  qkv[m][j] = sum_k x[m][k] * qkv_w[j][k]
// M=4096 (B*N), N=2304 (3C), K=768.  64x64 tile, 256 thr, 4x4 per thread.
// Epilogue scatters into q/k/v in [B,H,N,hd] layout. Each 64-col tile maps to
// exactly one (t, h) pair since head dim is 64 and tiles are 64-aligned.
// ---------------------------------------------------------------------------
__global__ __launch_bounds__(256) void qkv_gemm_k(const float* __restrict__ x,
                                                  const float* __restrict__ w,
                                                  float* __restrict__ qkv) {
    __shared__ float as[16][68];
    __shared__ float bs[16][68];
    const int bm = blockIdx.x;   // 0..63
    const int bn = blockIdx.y;   // 0..35
    const int tid = threadIdx.x;
    const int tx = tid & 15, ty = tid >> 4;
    const int lr = tid >> 2;          // 0..63
    const int lc = (tid & 3) * 4;     // 0,4,8,12
    const float* xrow = x + (size_t)(bm*64 + lr) * CC;
    const float* wrow = w + (size_t)(bn*64 + lr) * CC;
    float acc[4][4] = {};
    for (int k0 = 0; k0 < CC; k0 += 16) {
        float4 av = *(const float4*)(xrow + k0 + lc);
        float4 bv = *(const float4*)(wrow + k0 + lc);
        __syncthreads();
        as[lc+0][lr] = av.x; as[lc+1][lr] = av.y; as[lc+2][lr] = av.z; as[lc+3][lr] = av.w;
        bs[lc+0][lr] = bv.x; bs[lc+1][lr] = bv.y; bs[lc+2][lr] = bv.z; bs[lc+3][lr] = bv.w;
        __syncthreads();
#pragma unroll
        for (int k = 0; k < 16; ++k) {
            float4 a4 = *(const float4*)&as[k][ty*4];
            float4 b4 = *(const float4*)&bs[k][tx*4];
            float aa[4] = {a4.x, a4.y, a4.z, a4.w};
            float bb[4] = {b4.x, b4.y, b4.z, b4.w};
#pragma unroll
            for (int i = 0; i < 4; ++i)
#pragma unroll
                for (int j = 0; j < 4; ++j)
                    acc[i][j] += aa[i] * bb[j];
        }
    }
    // epilogue: j = bn*64 + tx*4 + jj ; t = bn/12 ; h = bn%12 ; d = tx*4+jj
    const int t = bn / 12;
    const int h = bn % 12;
#pragma unroll
    for (int i = 0; i < 4; ++i) {
        int m = bm*64 + ty*4 + i;
        int b = m >> 9, n = m & 511;
        float4 o4 = {acc[i][0], acc[i][1], acc[i][2], acc[i][3]};
        *(float4*)(qkv + (size_t)t*QKV_ELEMS
                        + ((size_t)(b*HH + h)*NN + n)*HD + tx*4) = o4;
    }
}

// ---------------------------------------------------------------------------
// Kernel 2: fused scores + exact top-k threshold + softmax.
// One block = one (b,h) and 16 rows.  256 threads.
//   phase 1: S[16][512] = q_tile @ k^T * 0.125  (thread owns 2 cols x 16 rows)
//   phase 2: per-row radix-select (4x 8-bit passes over ordered-uint keys)
//            finds the exact 90th-largest value; mask = s >= kth (ties kept,
//            matching jax semantics).  16 threads per row.
//   phase 3: masked softmax, write probs to attn output (zeros elsewhere).
// ---------------------------------------------------------------------------
__global__ __launch_bounds__(256) void attn_scores_k(const float* __restrict__ q,
                                                     const float* __restrict__ kmat,
                                                     const int* __restrict__ islast,
                                                     float* __restrict__ attn) {
    __shared__ float qs[16][64];
    __shared__ float s[16][512];
    __shared__ unsigned int hist[16][256];
    __shared__ float red[16][16];
    __shared__ unsigned int prefix_s[16];
    __shared__ int kk_s[16];

    const int blk = blockIdx.x;
    const int bh  = blk >> 5;      // 0..95
    const int rt  = blk & 31;      // row tile 0..31
    const int tid = threadIdx.x;
    const float* qb = q + ((size_t)bh*NN + rt*16) * HD;
    const float* kb = kmat + (size_t)bh*NN*HD;

    { // load q tile 16x64
        int r = tid >> 4, c = (tid & 15) * 4;
        *(float4*)&qs[r][c] = *(const float4*)(qb + r*HD + c);
    }
    __syncthreads();

    // ---- phase 1: scores ----
    const int c0 = tid * 2;
    const float* k0p = kb + (size_t)c0 * HD;
    const float* k1p = k0p + HD;
    float acc0[16], acc1[16];
#pragma unroll
    for (int r = 0; r < 16; ++r) { acc0[r] = 0.f; acc1[r] = 0.f; }
#pragma unroll
    for (int dd = 0; dd < 16; ++dd) {
        float4 ka = *(const float4*)(k0p + dd*4);
        float4 kc = *(const float4*)(k1p + dd*4);
#pragma unroll
        for (int r = 0; r < 16; ++r) {
            float4 q4 = *(const float4*)&qs[r][dd*4];
            acc0[r] += q4.x*ka.x + q4.y*ka.y + q4.z*ka.z + q4.w*ka.w;
            acc1[r] += q4.x*kc.x + q4.y*kc.y + q4.z*kc.z + q4.w*kc.w;
        }
    }
#pragma unroll
    for (int r = 0; r < 16; ++r) {
        s[r][c0]   = acc0[r] * 0.125f;
        s[r][c0+1] = acc1[r] * 0.125f;
    }
    __syncthreads();

    // ---- phase 2: exact kth-largest via radix select ----
    const int g    = tid >> 4;   // row within tile
    const int lane = tid & 15;   // thread within row-group
    const int last = islast[0];
    unsigned int kth_key = 0u;
    if (!last) {
        if (lane == 0) { prefix_s[g] = 0u; kk_s[g] = TOPK; }
        for (int pass = 3; pass >= 0; --pass) {
            for (int i = lane; i < 256; i += 16) hist[g][i] = 0u;
            __syncthreads();
            const unsigned int pf = prefix_s[g];
            const unsigned int maskhi = (pass == 3) ? 0u
                                        : (0xFFFFFFFFu << ((pass + 1) * 8));
            const int sh = pass * 8;
            for (int i = 0; i < 32; ++i) {
                float f = s[g][lane + 16*i];
                unsigned int u = __float_as_uint(f);
                u = (u & 0x80000000u) ? ~u : (u | 0x80000000u);
                if ((u & maskhi) == (pf & maskhi))
                    atomicAdd(&hist[g][(u >> sh) & 255u], 1u);
            }
            __syncthreads();
            if (lane == 0) {
                int kk = kk_s[g];
                unsigned int cum = 0u;
                for (int b2 = 255; b2 >= 0; --b2) {
                    unsigned int c = hist[g][b2];
                    if (cum + c >= (unsigned int)kk) {
                        prefix_s[g] |= ((unsigned int)b2 << sh);
                        kk_s[g] = kk - (int)cum;
                        break;
                    }
                    cum += c;
                }
            }
            __syncthreads();
        }
        kth_key = prefix_s[g];
    }

    // ---- phase 3: masked softmax ----
    float mx = -INFINITY;
    for (int i = 0; i < 32; ++i) mx = fmaxf(mx, s[g][lane + 16*i]);
    red[g][lane] = mx;
    __syncthreads();
#pragma unroll
    for (int j = 0; j < 16; ++j) mx = fmaxf(mx, red[g][j]);
    __syncthreads();   // red about to be reused for sums

    float sum = 0.f;
    for (int i = 0; i < 32; ++i) {
        float f = s[g][lane + 16*i];
        unsigned int u = __float_as_uint(f);
        u = (u & 0x80000000u) ? ~u : (u | 0x80000000u);
        float e = (last || (u >= kth_key)) ? __expf(f - mx) : 0.f;
        s[g][lane + 16*i] = e;
        sum += e;
    }
    red[g][lane] = sum;
    __syncthreads();
    float tot = 0.f;
#pragma unroll
    for (int j = 0; j < 16; ++j) tot += red[g][j];
    const float inv = 1.f / tot;

    float* arow = attn + ((size_t)bh*NN + rt*16 + g) * NN;
    for (int i = 0; i < 32; ++i)
        arow[lane + 16*i] = s[g][lane + 16*i] * inv;
}

// ---------------------------------------------------------------------------
// Kernel 3: O = P @ V per head, output in [B, N, C] layout (transpose fused
// into the store).  Block = one (b,h) and 64 rows; 64x64 output tile.
// ---------------------------------------------------------------------------
__global__ __launch_bounds__(256) void attn_pv_k(const float* __restrict__ attn,
                                                 const float* __restrict__ v,
                                                 float* __restrict__ o) {
    __shared__ float ps[32][68];
    __shared__ float vs[32][68];
    const int blk = blockIdx.x;     // 96*8
    const int bh  = blk >> 3;
    const int nt  = blk & 7;
    const int b = bh / HH, h = bh % HH;
    const int tid = threadIdx.x;
    const int tx = tid & 15, ty = tid >> 4;
    const float* pb = attn + ((size_t)bh*NN + nt*64) * NN;
    const float* vb = v + (size_t)bh*NN*HD;
    float acc[4][4] = {};
    for (int k0 = 0; k0 < NN; k0 += 32) {
        const int pr = tid >> 3;          // 0..31
        const int pc = (tid & 7) * 4;     // 0..28
        float4 p0 = *(const float4*)(pb + (size_t)pr*NN + k0 + pc);
        float4 p1 = *(const float4*)(pb + (size_t)(pr + 32)*NN + k0 + pc);
        const int vr = tid >> 4;          // 0..15
        const int vc = (tid & 15) * 4;
        float4 v0 = *(const float4*)(vb + (size_t)(k0 + vr)*HD + vc);
        float4 v1 = *(const float4*)(vb + (size_t)(k0 + vr + 16)*HD + vc);
        __syncthreads();
        ps[pc+0][pr] = p0.x; ps[pc+1][pr] = p0.y; ps[pc+2][pr] = p0.z; ps[pc+3][pr] = p0.w;
        ps[pc+0][pr+32] = p1.x; ps[pc+1][pr+32] = p1.y; ps[pc+2][pr+32] = p1.z; ps[pc+3][pr+32] = p1.w;
        *(float4*)&vs[vr][vc]      = v0;
        *(float4*)&vs[vr+16][vc]   = v1;
        __syncthreads();
#pragma unroll
        for (int k = 0; k < 32; ++k) {
            float4 a4 = *(const float4*)&ps[k][ty*4];
            float4 b4 = *(const float4*)&vs[k][tx*4];
            float aa[4] = {a4.x, a4.y, a4.z, a4.w};
            float bb[4] = {b4.x, b4.y, b4.z, b4.w};
#pragma unroll
            for (int i = 0; i < 4; ++i)
#pragma unroll
                for (int j = 0; j < 4; ++j)
                    acc[i][j] += aa[i] * bb[j];
        }
    }
#pragma unroll
    for (int i = 0; i < 4; ++i) {
        int n = nt*64 + ty*4 + i;
        float4 o4 = {acc[i][0], acc[i][1], acc[i][2], acc[i][3]};
        *(float4*)(o + ((size_t)(b*NN + n))*CC + h*HD + tx*4) = o4;
    }
}

// ---------------------------------------------------------------------------
// Kernel 4: final projection  y[m][j] = sum_k o[m][k]*proj_w[j][k] + bias[j]
// M=4096, N=768, K=768. Same tile structure as kernel 1; writes d_out[0] area.
// ---------------------------------------------------------------------------
__global__ __launch_bounds__(256) void proj_gemm_k(const float* __restrict__ o,
                                                   const float* __restrict__ w,
                                                   const float* __restrict__ bias,
                                                   float* __restrict__ y) {
    __shared__ float as[16][68];
    __shared__ float bs[16][68];
    const int bm = blockIdx.x;   // 0..63
    const int bn = blockIdx.y;   // 0..11
    const int tid = threadIdx.x;
    const int tx = tid & 15, ty = tid >> 4;
    const int lr = tid >> 2;
    const int lc = (tid & 3) * 4;
    const float* orow = o + (size_t)(bm*64 + lr) * CC;
    const float* wrow = w + (size_t)(bn*64 + lr) * CC;
    float acc[4][4] = {};
    for (int k0 = 0; k0 < CC; k0 += 16) {
        float4 av = *(const float4*)(orow + k0 + lc);
        float4 bv = *(const float4*)(wrow + k0 + lc);
        __syncthreads();
        as[lc+0][lr] = av.x; as[lc+1][lr] = av.y; as[lc+2][lr] = av.z; as[lc+3][lr] = av.w;
        bs[lc+0][lr] = bv.x; bs[lc+1][lr] = bv.y; bs[lc+2][lr] = bv.z; bs[lc+3][lr] = bv.w;
        __syncthreads();
#pragma unroll
        for (int k = 0; k < 16; ++k) {
            float4 a4 = *(const float4*)&as[k][ty*4];
            float4 b4 = *(const float4*)&bs[k][tx*4];
            float aa[4] = {a4.x, a4.y, a4.z, a4.w};
            float bb[4] = {b4.x, b4.y, b4.z, b4.w};
#pragma unroll
            for (int i = 0; i < 4; ++i)
#pragma unroll
                for (int j = 0; j < 4; ++j)
                    acc[i][j] += aa[i] * bb[j];
        }
    }
    float4 bias4 = *(const float4*)(bias + bn*64 + tx*4);
#pragma unroll
    for (int i = 0; i < 4; ++i) {
        int m = bm*64 + ty*4 + i;
        float4 o4 = {acc[i][0] + bias4.x, acc[i][1] + bias4.y,
                     acc[i][2] + bias4.z, acc[i][3] + bias4.w};
        *(float4*)(y + (size_t)m*CC + bn*64 + tx*4) = o4;
    }
}

// ---------------------------------------------------------------------------
extern "C" void kernel_launch(void* const* d_in, const int* in_sizes, int n_in,
                              void* d_out, int out_size, void* d_ws, size_t ws_size,
                              hipStream_t stream) {
    const float* x      = (const float*)d_in[0];
    const float* qkv_w  = (const float*)d_in[1];
    const float* proj_w = (const float*)d_in[2];
    const float* proj_b = (const float*)d_in[3];
    const int*   islast = (const int*)d_in[4];

    float* out  = (float*)d_out;                       // [B,N,C]
    float* attn = out + (size_t)BB*NN*CC;              // [B,H,N,N]

    float* ws = (float*)d_ws;
    float* q  = ws;                                    // [B,H,N,hd]
    float* k  = ws + (size_t)QKV_ELEMS;
    float* v  = ws + 2*(size_t)QKV_ELEMS;
    float* o  = ws + 3*(size_t)QKV_ELEMS;              // [B,N,C]

    qkv_gemm_k   <<<dim3(64, 36), 256, 0, stream>>>(x, qkv_w, q);
    attn_scores_k<<<dim3(96*32),  256, 0, stream>>>(q, k, islast, attn);
    attn_pv_k    <<<dim3(96*8),   256, 0, stream>>>(attn, v, o);
    proj_gemm_k  <<<dim3(64, 12), 256, 0, stream>>>(o, proj_w, proj_b, out);
}

// Round 2
// 600.152 us; speedup vs baseline: 2.2758x; 2.2758x over previous
//
#include <hip/hip_runtime.h>
#include <math.h>

#define BB 8
#define NN 512
#define CC 768
#define HH 12
#define HD 64
#define TOPK 90
#define QKV_ELEMS (BB*HH*NN*HD)   // 3145728 elements per q/k/v tensor

// ---------------------------------------------------------------------------
// Kernel 1: QKV GEMM.  qkv[m][j] = sum_k x[m][k] * qkv_w[j][k]
// M=4096 (B*N), N=2304 (3C), K=768.  64x64 tile, 256 thr, 4x4 per thread.
// ---------------------------------------------------------------------------
__global__ __launch_bounds__(256) void qkv_gemm_k(const float* __restrict__ x,
                                                  const float* __restrict__ w,
                                                  float* __restrict__ qkv) {
    __shared__ float as[16][68];
    __shared__ float bs[16][68];
    const int bm = blockIdx.x;   // 0..63
    const int bn = blockIdx.y;   // 0..35
    const int tid = threadIdx.x;
    const int tx = tid & 15, ty = tid >> 4;
    const int lr = tid >> 2;          // 0..63
    const int lc = (tid & 3) * 4;     // 0,4,8,12
    const float* xrow = x + (size_t)(bm*64 + lr) * CC;
    const float* wrow = w + (size_t)(bn*64 + lr) * CC;
    float acc[4][4] = {};
    for (int k0 = 0; k0 < CC; k0 += 16) {
        float4 av = *(const float4*)(xrow + k0 + lc);
        float4 bv = *(const float4*)(wrow + k0 + lc);
        __syncthreads();
        as[lc+0][lr] = av.x; as[lc+1][lr] = av.y; as[lc+2][lr] = av.z; as[lc+3][lr] = av.w;
        bs[lc+0][lr] = bv.x; bs[lc+1][lr] = bv.y; bs[lc+2][lr] = bv.z; bs[lc+3][lr] = bv.w;
        __syncthreads();
#pragma unroll
        for (int k = 0; k < 16; ++k) {
            float4 a4 = *(const float4*)&as[k][ty*4];
            float4 b4 = *(const float4*)&bs[k][tx*4];
            float aa[4] = {a4.x, a4.y, a4.z, a4.w};
            float bb[4] = {b4.x, b4.y, b4.z, b4.w};
#pragma unroll
            for (int i = 0; i < 4; ++i)
#pragma unroll
                for (int j = 0; j < 4; ++j)
                    acc[i][j] += aa[i] * bb[j];
        }
    }
    const int t = bn / 12;
    const int h = bn % 12;
#pragma unroll
    for (int i = 0; i < 4; ++i) {
        int m = bm*64 + ty*4 + i;
        int b = m >> 9, n = m & 511;
        float4 o4 = {acc[i][0], acc[i][1], acc[i][2], acc[i][3]};
        *(float4*)(qkv + (size_t)t*QKV_ELEMS
                        + ((size_t)(b*HH + h)*NN + n)*HD + tx*4) = o4;
    }
}

// ---------------------------------------------------------------------------
// Kernel 2 (rewritten): fused scores + exact top-k + softmax.
// Block = one (b,h) x 16 rows, 256 threads = 4 waves, one wave per 4 rows.
// Scores live in REGISTERS: lane l owns columns l + 64*j (j=0..7), 4 rows
// => sreg[4][8].  K staged in LDS 64x66 tiles (2-way bank alias = free).
// Radix select: per-wave 256-bucket LDS histogram (8 atomics/lane) + 64-lane
// shuffle suffix-scan (no serial 256-walk, no __syncthreads in phase 2/3).
// ---------------------------------------------------------------------------
__global__ __launch_bounds__(256) void attn_scores_k(const float* __restrict__ q,
                                                     const float* __restrict__ kmat,
                                                     const int* __restrict__ islast,
                                                     float* __restrict__ attn) {
    __shared__ float qs[16][64];          // broadcast reads -> no pad needed
    __shared__ float ks[64][66];          // pad 66: float2 reads 2-way (free)
    __shared__ unsigned int hist[4][256]; // per-wave histogram

    const int blk  = blockIdx.x;
    const int bh   = blk >> 5;      // 0..95
    const int rt   = blk & 31;      // row tile 0..31
    const int tid  = threadIdx.x;
    const int wv   = tid >> 6;      // wave 0..3
    const int lane = tid & 63;
    const float* qb = q + ((size_t)bh*NN + rt*16) * HD;
    const float* kb = kmat + (size_t)bh*NN*HD;

    { // load q tile 16x64 (coalesced, 4KB contiguous)
        int r = tid >> 4, c = (tid & 15) * 4;
        *(float4*)&qs[r][c] = *(const float4*)(qb + r*HD + c);
    }

    const int r0 = wv * 4;          // this wave's first row within the tile
    float sreg[4][8];               // sreg[r][kt] = score[row r][kt*64+lane]

    // ---- phase 1: scores, K staged in 8 tiles of 64 rows ----
    for (int kt = 0; kt < 8; ++kt) {
        __syncthreads();   // (kt=0: qs/ks visibility; else: readers done w/ ks)
#pragma unroll
        for (int i = 0; i < 4; ++i) {
            int c = tid + 256*i;            // 1024 float4 chunks
            int row = c >> 4, col = (c & 15) * 4;
            float4 g = *(const float4*)(kb + (size_t)(kt*64 + row)*HD + col);
            *(float2*)&ks[row][col]   = make_float2(g.x, g.y);
            *(float2*)&ks[row][col+2] = make_float2(g.z, g.w);
        }
        __syncthreads();
        float a0 = 0.f, a1 = 0.f, a2 = 0.f, a3 = 0.f;
#pragma unroll
        for (int d4 = 0; d4 < 16; ++d4) {
            float2 kA = *(const float2*)&ks[lane][d4*4];
            float2 kB = *(const float2*)&ks[lane][d4*4 + 2];
            float4 q0 = *(const float4*)&qs[r0+0][d4*4];
            float4 q1 = *(const float4*)&qs[r0+1][d4*4];
            float4 q2 = *(const float4*)&qs[r0+2][d4*4];
            float4 q3 = *(const float4*)&qs[r0+3][d4*4];
            a0 += q0.x*kA.x + q0.y*kA.y + q0.z*kB.x + q0.w*kB.y;
            a1 += q1.x*kA.x + q1.y*kA.y + q1.z*kB.x + q1.w*kB.y;
            a2 += q2.x*kA.x + q2.y*kA.y + q2.z*kB.x + q2.w*kB.y;
            a3 += q3.x*kA.x + q3.y*kA.y + q3.z*kB.x + q3.w*kB.y;
        }
        sreg[0][kt] = a0 * 0.125f;
        sreg[1][kt] = a1 * 0.125f;
        sreg[2][kt] = a2 * 0.125f;
        sreg[3][kt] = a3 * 0.125f;
    }

    // ---- phase 2+3 per row: radix select + masked softmax (wave-local) ----
    const int last = islast[0];
    float* abase = attn + ((size_t)bh*NN + rt*16 + r0) * NN;

#pragma unroll
    for (int r = 0; r < 4; ++r) {
        unsigned int kth_key = 0u;
        if (!last) {
            unsigned int u8[8];
#pragma unroll
            for (int j = 0; j < 8; ++j) {
                unsigned int u = __float_as_uint(sreg[r][j]);
                u8[j] = (u & 0x80000000u) ? ~u : (u | 0x80000000u);
            }
            unsigned int prefix = 0u;
            int kk = TOPK;
#pragma unroll
            for (int pass = 3; pass >= 0; --pass) {
                hist[wv][lane]       = 0u;
                hist[wv][lane + 64]  = 0u;
                hist[wv][lane + 128] = 0u;
                hist[wv][lane + 192] = 0u;
                asm volatile("s_waitcnt lgkmcnt(0)" ::: "memory");
                const unsigned int maskhi = (pass == 3) ? 0u
                                          : (0xFFFFFFFFu << ((pass + 1) * 8));
                const int sh = pass * 8;
#pragma unroll
                for (int j = 0; j < 8; ++j) {
                    if ((u8[j] & maskhi) == (prefix & maskhi))
                        atomicAdd(&hist[wv][(u8[j] >> sh) & 255u], 1u);
                }
                asm volatile("s_waitcnt lgkmcnt(0)" ::: "memory");
                // lane l covers buckets 252-4l .. 255-4l (descending chunks)
                const int base = 252 - 4*lane;
                unsigned int h0 = hist[wv][base + 3];
                unsigned int h1 = hist[wv][base + 2];
                unsigned int h2 = hist[wv][base + 1];
                unsigned int h3 = hist[wv][base + 0];
                unsigned int p = h0 + h1 + h2 + h3;
                unsigned int C = p;
#pragma unroll
                for (int off = 1; off < 64; off <<= 1) {
                    unsigned int t = __shfl_up(C, off);
                    if (lane >= off) C += t;
                }
                unsigned long long bal = __ballot((int)C >= kk);
                int wl = (int)__ffsll(bal) - 1;
                unsigned int Cw = __shfl(C, wl);
                unsigned int pw = __shfl(p, wl);
                unsigned int g0 = __shfl(h0, wl);
                unsigned int g1 = __shfl(h1, wl);
                unsigned int g2 = __shfl(h2, wl);
                int cum = (int)(Cw - pw);
                const int basew = 252 - 4*wl;
                int nb;
                if      (cum + (int)g0 >= kk)            { nb = basew + 3; kk -= cum; }
                else if (cum + (int)(g0+g1) >= kk)       { nb = basew + 2; kk -= cum + (int)g0; }
                else if (cum + (int)(g0+g1+g2) >= kk)    { nb = basew + 1; kk -= cum + (int)(g0+g1); }
                else                                     { nb = basew;     kk -= cum + (int)(g0+g1+g2); }
                prefix |= ((unsigned int)nb) << sh;
            }
            kth_key = prefix;
        }

        // masked softmax (wave shuffle reductions)
        float mx = -INFINITY;
#pragma unroll
        for (int j = 0; j < 8; ++j) mx = fmaxf(mx, sreg[r][j]);
#pragma unroll
        for (int off = 32; off >= 1; off >>= 1) mx = fmaxf(mx, __shfl_xor(mx, off));
        float sum = 0.f;
#pragma unroll
        for (int j = 0; j < 8; ++j) {
            unsigned int u = __float_as_uint(sreg[r][j]);
            u = (u & 0x80000000u) ? ~u : (u | 0x80000000u);
            float e = (last || u >= kth_key) ? __expf(sreg[r][j] - mx) : 0.f;
            sreg[r][j] = e;
            sum += e;
        }
#pragma unroll
        for (int off = 32; off >= 1; off >>= 1) sum += __shfl_xor(sum, off);
        const float inv = 1.f / sum;
        float* arow = abase + (size_t)r * NN;
#pragma unroll
        for (int j = 0; j < 8; ++j) arow[j*64 + lane] = sreg[r][j] * inv;
    }
}

// ---------------------------------------------------------------------------
// Kernel 3: O = P @ V per head, output in [B, N, C] layout.
// ---------------------------------------------------------------------------
__global__ __launch_bounds__(256) void attn_pv_k(const float* __restrict__ attn,
                                                 const float* __restrict__ v,
                                                 float* __restrict__ o) {
    __shared__ float ps[32][68];
    __shared__ float vs[32][68];
    const int blk = blockIdx.x;     // 96*8
    const int bh  = blk >> 3;
    const int nt  = blk & 7;
    const int b = bh / HH, h = bh % HH;
    const int tid = threadIdx.x;
    const int tx = tid & 15, ty = tid >> 4;
    const float* pb = attn + ((size_t)bh*NN + nt*64) * NN;
    const float* vb = v + (size_t)bh*NN*HD;
    float acc[4][4] = {};
    for (int k0 = 0; k0 < NN; k0 += 32) {
        const int pr = tid >> 3;          // 0..31
        const int pc = (tid & 7) * 4;     // 0..28
        float4 p0 = *(const float4*)(pb + (size_t)pr*NN + k0 + pc);
        float4 p1 = *(const float4*)(pb + (size_t)(pr + 32)*NN + k0 + pc);
        const int vr = tid >> 4;          // 0..15
        const int vc = (tid & 15) * 4;
        float4 v0 = *(const float4*)(vb + (size_t)(k0 + vr)*HD + vc);
        float4 v1 = *(const float4*)(vb + (size_t)(k0 + vr + 16)*HD + vc);
        __syncthreads();
        ps[pc+0][pr] = p0.x; ps[pc+1][pr] = p0.y; ps[pc+2][pr] = p0.z; ps[pc+3][pr] = p0.w;
        ps[pc+0][pr+32] = p1.x; ps[pc+1][pr+32] = p1.y; ps[pc+2][pr+32] = p1.z; ps[pc+3][pr+32] = p1.w;
        *(float4*)&vs[vr][vc]      = v0;
        *(float4*)&vs[vr+16][vc]   = v1;
        __syncthreads();
#pragma unroll
        for (int k = 0; k < 32; ++k) {
            float4 a4 = *(const float4*)&ps[k][ty*4];
            float4 b4 = *(const float4*)&vs[k][tx*4];
            float aa[4] = {a4.x, a4.y, a4.z, a4.w};
            float bb[4] = {b4.x, b4.y, b4.z, b4.w};
#pragma unroll
            for (int i = 0; i < 4; ++i)
#pragma unroll
                for (int j = 0; j < 4; ++j)
                    acc[i][j] += aa[i] * bb[j];
        }
    }
#pragma unroll
    for (int i = 0; i < 4; ++i) {
        int n = nt*64 + ty*4 + i;
        float4 o4 = {acc[i][0], acc[i][1], acc[i][2], acc[i][3]};
        *(float4*)(o + ((size_t)(b*NN + n))*CC + h*HD + tx*4) = o4;
    }
}

// ---------------------------------------------------------------------------
// Kernel 4: final projection  y = o @ proj_w^T + bias
// ---------------------------------------------------------------------------
__global__ __launch_bounds__(256) void proj_gemm_k(const float* __restrict__ o,
                                                   const float* __restrict__ w,
                                                   const float* __restrict__ bias,
                                                   float* __restrict__ y) {
    __shared__ float as[16][68];
    __shared__ float bs[16][68];
    const int bm = blockIdx.x;   // 0..63
    const int bn = blockIdx.y;   // 0..11
    const int tid = threadIdx.x;
    const int tx = tid & 15, ty = tid >> 4;
    const int lr = tid >> 2;
    const int lc = (tid & 3) * 4;
    const float* orow = o + (size_t)(bm*64 + lr) * CC;
    const float* wrow = w + (size_t)(bn*64 + lr) * CC;
    float acc[4][4] = {};
    for (int k0 = 0; k0 < CC; k0 += 16) {
        float4 av = *(const float4*)(orow + k0 + lc);
        float4 bv = *(const float4*)(wrow + k0 + lc);
        __syncthreads();
        as[lc+0][lr] = av.x; as[lc+1][lr] = av.y; as[lc+2][lr] = av.z; as[lc+3][lr] = av.w;
        bs[lc+0][lr] = bv.x; bs[lc+1][lr] = bv.y; bs[lc+2][lr] = bv.z; bs[lc+3][lr] = bv.w;
        __syncthreads();
#pragma unroll
        for (int k = 0; k < 16; ++k) {
            float4 a4 = *(const float4*)&as[k][ty*4];
            float4 b4 = *(const float4*)&bs[k][tx*4];
            float aa[4] = {a4.x, a4.y, a4.z, a4.w};
            float bb[4] = {b4.x, b4.y, b4.z, b4.w};
#pragma unroll
            for (int i = 0; i < 4; ++i)
#pragma unroll
                for (int j = 0; j < 4; ++j)
                    acc[i][j] += aa[i] * bb[j];
        }
    }
    float4 bias4 = *(const float4*)(bias + bn*64 + tx*4);
#pragma unroll
    for (int i = 0; i < 4; ++i) {
        int m = bm*64 + ty*4 + i;
        float4 o4 = {acc[i][0] + bias4.x, acc[i][1] + bias4.y,
                     acc[i][2] + bias4.z, acc[i][3] + bias4.w};
        *(float4*)(y + (size_t)m*CC + bn*64 + tx*4) = o4;
    }
}

// ---------------------------------------------------------------------------
extern "C" void kernel_launch(void* const* d_in, const int* in_sizes, int n_in,
                              void* d_out, int out_size, void* d_ws, size_t ws_size,
                              hipStream_t stream) {
    const float* x      = (const float*)d_in[0];
    const float* qkv_w  = (const float*)d_in[1];
    const float* proj_w = (const float*)d_in[2];
    const float* proj_b = (const float*)d_in[3];
    const int*   islast = (const int*)d_in[4];

    float* out  = (float*)d_out;                       // [B,N,C]
    float* attn = out + (size_t)BB*NN*CC;              // [B,H,N,N]

    float* ws = (float*)d_ws;
    float* q  = ws;                                    // [B,H,N,hd]
    float* k  = ws + (size_t)QKV_ELEMS;
    float* v  = ws + 2*(size_t)QKV_ELEMS;
    float* o  = ws + 3*(size_t)QKV_ELEMS;              // [B,N,C]

    qkv_gemm_k   <<<dim3(64, 36), 256, 0, stream>>>(x, qkv_w, q);
    attn_scores_k<<<dim3(96*32),  256, 0, stream>>>(q, k, islast, attn);
    attn_pv_k    <<<dim3(96*8),   256, 0, stream>>>(attn, v, o);
    proj_gemm_k  <<<dim3(64, 12), 256, 0, stream>>>(o, proj_w, proj_b, out);
}

// Round 3
// 443.167 us; speedup vs baseline: 3.0819x; 1.3542x over previous
//
#include <hip/hip_runtime.h>
#include <math.h>

#define BB 8
#define NN 512
#define CC 768
#define HH 12
#define HD 64
#define TOPK 90
#define QKV_ELEMS (BB*HH*NN*HD)   // 3145728 elements per q/k/v tensor
#define KC 2304                   // split-K: 3*768

typedef __attribute__((ext_vector_type(8))) short short8;   // 8 bf16 = 4 VGPR
typedef __attribute__((ext_vector_type(4))) float floatx4;  // MFMA C/D

__device__ inline unsigned short f2bf(float f) {
    unsigned int u = __float_as_uint(f);
    u += 0x7FFFu + ((u >> 16) & 1u);           // RNE on magnitude bits
    return (unsigned short)(u >> 16);
}
__device__ inline float bf2f(unsigned short h) {
    return __uint_as_float(((unsigned int)h) << 16);
}

// ---------------------------------------------------------------------------
// Split kernels: fp32 [rows][768] -> bf16 [rows][2304].
// IS_A: blocks [hi | hi | lo]   (activations)
// !IS_A: blocks [hi | lo | hi]  (weights)  so term k-blocks give hh + hl + lh.
// ---------------------------------------------------------------------------
template<bool IS_A>
__global__ __launch_bounds__(256) void split_k(const float* __restrict__ in,
                                               unsigned short* __restrict__ o2,
                                               int total /* rows*768/4 */) {
    int idx = blockIdx.x * 256 + threadIdx.x;
    if (idx >= total) return;
    int e = idx * 4;
    int m = e / CC, kk = e - m * CC;
    float4 f = *(const float4*)(in + e);
    ushort4 hi, lo;
    hi.x = f2bf(f.x); lo.x = f2bf(f.x - bf2f(hi.x));
    hi.y = f2bf(f.y); lo.y = f2bf(f.y - bf2f(hi.y));
    hi.z = f2bf(f.z); lo.z = f2bf(f.z - bf2f(hi.z));
    hi.w = f2bf(f.w); lo.w = f2bf(f.w - bf2f(hi.w));
    unsigned short* base = o2 + (size_t)m * KC + kk;
    *(ushort4*)(base)        = hi;
    *(ushort4*)(base + CC)   = IS_A ? hi : lo;
    *(ushort4*)(base + 2*CC) = IS_A ? lo : hi;
}

// ---------------------------------------------------------------------------
// Split-bf16 MFMA GEMM: out[m][n] = sum_k A'[m][k] B'[n][k], K'=2304.
// 128x128 tile, 256 thr = 4 waves (2x2 of 64x64), 16x16x32 bf16 MFMA,
// BK=32, global_load_lds width-16 staging, XOR octet swizzle (2-way banks).
// QKV_EPI: scatter into q/k/v [3][B,H,N,hd]; else: out[m][NCOLS]+bias.
// ---------------------------------------------------------------------------
template<int NCOLS, bool QKV_EPI>
__global__ __launch_bounds__(256) void gemm_split(const unsigned short* __restrict__ A,
                                                  const unsigned short* __restrict__ Bm,
                                                  const float* __restrict__ bias,
                                                  float* __restrict__ out) {
    __shared__ char lds[16384];          // A tile 8KB @0, B tile 8KB @8192
    const int bm = blockIdx.x, bn = blockIdx.y;
    const int tid  = threadIdx.x;
    const int wave = tid >> 6, lane = tid & 63;
    const int wm = wave >> 1, wn = wave & 1;
    const int quad = lane >> 4, r = lane & 15;

    // ---- staging address setup: chunk c -> m=c>>2, LDS octet o'=c&3,
    //      global octet fetched o = o' ^ ((m>>1)&3)
    const int cA0 = tid, cA1 = tid + 256;
    const int mA0 = cA0 >> 2, oA0 = (cA0 & 3) ^ ((mA0 >> 1) & 3);
    const int mA1 = cA1 >> 2, oA1 = (cA1 & 3) ^ ((mA1 >> 1) & 3);
    const unsigned short* gA0 = A  + (size_t)(bm*128 + mA0) * KC + oA0*8;
    const unsigned short* gA1 = A  + (size_t)(bm*128 + mA1) * KC + oA1*8;
    const unsigned short* gB0 = Bm + (size_t)(bn*128 + mA0) * KC + oA0*8;
    const unsigned short* gB1 = Bm + (size_t)(bn*128 + mA1) * KC + oA1*8;
    // wave-uniform LDS bases: inst j, wave w -> (j*256 + w*64)*16
    char* lA0 = lds + (wave*64)*16;
    char* lA1 = lds + (256 + wave*64)*16;
    char* lB0 = lds + 8192 + (wave*64)*16;
    char* lB1 = lds + 8192 + (256 + wave*64)*16;

    // fragment LDS offsets (swizzle: octet' = quad ^ ((r>>1)&3))
    const int octsel = quad ^ ((r >> 1) & 3);
    int aoff[4], boff[4];
#pragma unroll
    for (int i = 0; i < 4; ++i) {
        aoff[i] = ((wm*64 + i*16 + r)*4 + octsel) * 16;
        boff[i] = 8192 + ((wn*64 + i*16 + r)*4 + octsel) * 16;
    }

    floatx4 acc[4][4];
#pragma unroll
    for (int i = 0; i < 4; ++i)
#pragma unroll
        for (int j = 0; j < 4; ++j)
            acc[i][j] = (floatx4){0.f, 0.f, 0.f, 0.f};

    for (int it = 0; it < KC/32; ++it) {
        __syncthreads();   // all waves done reading previous tile
        __builtin_amdgcn_global_load_lds((const __attribute__((address_space(1))) unsigned int*)gA0,
                                         (__attribute__((address_space(3))) unsigned int*)lA0, 16, 0, 0);
        __builtin_amdgcn_global_load_lds((const __attribute__((address_space(1))) unsigned int*)gA1,
                                         (__attribute__((address_space(3))) unsigned int*)lA1, 16, 0, 0);
        __builtin_amdgcn_global_load_lds((const __attribute__((address_space(1))) unsigned int*)gB0,
                                         (__attribute__((address_space(3))) unsigned int*)lB0, 16, 0, 0);
        __builtin_amdgcn_global_load_lds((const __attribute__((address_space(1))) unsigned int*)gB1,
                                         (__attribute__((address_space(3))) unsigned int*)lB1, 16, 0, 0);
        gA0 += 32; gA1 += 32; gB0 += 32; gB1 += 32;
        asm volatile("s_waitcnt vmcnt(0)" ::: "memory");
        __syncthreads();

        short8 af[4], bf[4];
#pragma unroll
        for (int i = 0; i < 4; ++i) af[i] = *(const short8*)(lds + aoff[i]);
#pragma unroll
        for (int j = 0; j < 4; ++j) bf[j] = *(const short8*)(lds + boff[j]);
#pragma unroll
        for (int i = 0; i < 4; ++i)
#pragma unroll
            for (int j = 0; j < 4; ++j)
                acc[i][j] = __builtin_amdgcn_mfma_f32_16x16x32_bf16(af[i], bf[j], acc[i][j], 0, 0, 0);
    }

    // ---- epilogue ----  D: col = lane&15 (=r), row = quad*4 + e
    if (QKV_EPI) {
#pragma unroll
        for (int j = 0; j < 4; ++j) {
            int col = bn*128 + wn*64 + j*16 + r;     // [0,2304)
            int t = col / CC;
            int rem = col - t*CC;
            int h = rem >> 6, d = rem & 63;
            float* obase = out + (size_t)t*QKV_ELEMS + d;
#pragma unroll
            for (int i = 0; i < 4; ++i) {
#pragma unroll
                for (int e = 0; e < 4; ++e) {
                    int m = bm*128 + wm*64 + i*16 + quad*4 + e;
                    int b = m >> 9, nrow = m & 511;
                    obase[((size_t)(b*HH + h)*NN + nrow)*HD] = acc[i][j][e];
                }
            }
        }
    } else {
#pragma unroll
        for (int j = 0; j < 4; ++j) {
            int col = bn*128 + wn*64 + j*16 + r;     // [0,NCOLS)
            float bv = bias[col];
#pragma unroll
            for (int i = 0; i < 4; ++i) {
#pragma unroll
                for (int e = 0; e < 4; ++e) {
                    int m = bm*128 + wm*64 + i*16 + quad*4 + e;
                    out[(size_t)m*NCOLS + col] = acc[i][j][e] + bv;
                }
            }
        }
    }
}

// ---------------------------------------------------------------------------
// Fused scores + exact top-k + softmax (unchanged from round 2).
// ---------------------------------------------------------------------------
__global__ __launch_bounds__(256) void attn_scores_k(const float* __restrict__ q,
                                                     const float* __restrict__ kmat,
                                                     const int* __restrict__ islast,
                                                     float* __restrict__ attn) {
    __shared__ float qs[16][64];
    __shared__ float ks[64][66];
    __shared__ unsigned int hist[4][256];

    const int blk  = blockIdx.x;
    const int bh   = blk >> 5;
    const int rt   = blk & 31;
    const int tid  = threadIdx.x;
    const int wv   = tid >> 6;
    const int lane = tid & 63;
    const float* qb = q + ((size_t)bh*NN + rt*16) * HD;
    const float* kb = kmat + (size_t)bh*NN*HD;

    {
        int r = tid >> 4, c = (tid & 15) * 4;
        *(float4*)&qs[r][c] = *(const float4*)(qb + r*HD + c);
    }

    const int r0 = wv * 4;
    float sreg[4][8];

    for (int kt = 0; kt < 8; ++kt) {
        __syncthreads();
#pragma unroll
        for (int i = 0; i < 4; ++i) {
            int c = tid + 256*i;
            int row = c >> 4, col = (c & 15) * 4;
            float4 g = *(const float4*)(kb + (size_t)(kt*64 + row)*HD + col);
            *(float2*)&ks[row][col]   = make_float2(g.x, g.y);
            *(float2*)&ks[row][col+2] = make_float2(g.z, g.w);
        }
        __syncthreads();
        float a0 = 0.f, a1 = 0.f, a2 = 0.f, a3 = 0.f;
#pragma unroll
        for (int d4 = 0; d4 < 16; ++d4) {
            float2 kA = *(const float2*)&ks[lane][d4*4];
            float2 kB = *(const float2*)&ks[lane][d4*4 + 2];
            float4 q0 = *(const float4*)&qs[r0+0][d4*4];
            float4 q1 = *(const float4*)&qs[r0+1][d4*4];
            float4 q2 = *(const float4*)&qs[r0+2][d4*4];
            float4 q3 = *(const float4*)&qs[r0+3][d4*4];
            a0 += q0.x*kA.x + q0.y*kA.y + q0.z*kB.x + q0.w*kB.y;
            a1 += q1.x*kA.x + q1.y*kA.y + q1.z*kB.x + q1.w*kB.y;
            a2 += q2.x*kA.x + q2.y*kA.y + q2.z*kB.x + q2.w*kB.y;
            a3 += q3.x*kA.x + q3.y*kA.y + q3.z*kB.x + q3.w*kB.y;
        }
        sreg[0][kt] = a0 * 0.125f;
        sreg[1][kt] = a1 * 0.125f;
        sreg[2][kt] = a2 * 0.125f;
        sreg[3][kt] = a3 * 0.125f;
    }

    const int last = islast[0];
    float* abase = attn + ((size_t)bh*NN + rt*16 + r0) * NN;

#pragma unroll
    for (int r = 0; r < 4; ++r) {
        unsigned int kth_key = 0u;
        if (!last) {
            unsigned int u8[8];
#pragma unroll
            for (int j = 0; j < 8; ++j) {
                unsigned int u = __float_as_uint(sreg[r][j]);
                u8[j] = (u & 0x80000000u) ? ~u : (u | 0x80000000u);
            }
            unsigned int prefix = 0u;
            int kk = TOPK;
#pragma unroll
            for (int pass = 3; pass >= 0; --pass) {
                hist[wv][lane]       = 0u;
                hist[wv][lane + 64]  = 0u;
                hist[wv][lane + 128] = 0u;
                hist[wv][lane + 192] = 0u;
                asm volatile("s_waitcnt lgkmcnt(0)" ::: "memory");
                const unsigned int maskhi = (pass == 3) ? 0u
                                          : (0xFFFFFFFFu << ((pass + 1) * 8));
                const int sh = pass * 8;
#pragma unroll
                for (int j = 0; j < 8; ++j) {
                    if ((u8[j] & maskhi) == (prefix & maskhi))
                        atomicAdd(&hist[wv][(u8[j] >> sh) & 255u], 1u);
                }
                asm volatile("s_waitcnt lgkmcnt(0)" ::: "memory");
                const int base = 252 - 4*lane;
                unsigned int h0 = hist[wv][base + 3];
                unsigned int h1 = hist[wv][base + 2];
                unsigned int h2 = hist[wv][base + 1];
                unsigned int h3 = hist[wv][base + 0];
                unsigned int p = h0 + h1 + h2 + h3;
                unsigned int C = p;
#pragma unroll
                for (int off = 1; off < 64; off <<= 1) {
                    unsigned int t = __shfl_up(C, off);
                    if (lane >= off) C += t;
                }
                unsigned long long bal = __ballot((int)C >= kk);
                int wl = (int)__ffsll(bal) - 1;
                unsigned int Cw = __shfl(C, wl);
                unsigned int pw = __shfl(p, wl);
                unsigned int g0 = __shfl(h0, wl);
                unsigned int g1 = __shfl(h1, wl);
                unsigned int g2 = __shfl(h2, wl);
                int cum = (int)(Cw - pw);
                const int basew = 252 - 4*wl;
                int nb;
                if      (cum + (int)g0 >= kk)            { nb = basew + 3; kk -= cum; }
                else if (cum + (int)(g0+g1) >= kk)       { nb = basew + 2; kk -= cum + (int)g0; }
                else if (cum + (int)(g0+g1+g2) >= kk)    { nb = basew + 1; kk -= cum + (int)(g0+g1); }
                else                                     { nb = basew;     kk -= cum + (int)(g0+g1+g2); }
                prefix |= ((unsigned int)nb) << sh;
            }
            kth_key = prefix;
        }

        float mx = -INFINITY;
#pragma unroll
        for (int j = 0; j < 8; ++j) mx = fmaxf(mx, sreg[r][j]);
#pragma unroll
        for (int off = 32; off >= 1; off >>= 1) mx = fmaxf(mx, __shfl_xor(mx, off));
        float sum = 0.f;
#pragma unroll
        for (int j = 0; j < 8; ++j) {
            unsigned int u = __float_as_uint(sreg[r][j]);
            u = (u & 0x80000000u) ? ~u : (u | 0x80000000u);
            float e = (last || u >= kth_key) ? __expf(sreg[r][j] - mx) : 0.f;
            sreg[r][j] = e;
            sum += e;
        }
#pragma unroll
        for (int off = 32; off >= 1; off >>= 1) sum += __shfl_xor(sum, off);
        const float inv = 1.f / sum;
        float* arow = abase + (size_t)r * NN;
#pragma unroll
        for (int j = 0; j < 8; ++j) arow[j*64 + lane] = sreg[r][j] * inv;
    }
}

// ---------------------------------------------------------------------------
// O = P @ V per head; epilogue writes SPLIT-BF16 o directly: [hi|hi|lo]
// into Ao [4096][2304] for the proj MFMA GEMM.
// ---------------------------------------------------------------------------
__global__ __launch_bounds__(256) void attn_pv_k(const float* __restrict__ attn,
                                                 const float* __restrict__ v,
                                                 unsigned short* __restrict__ Ao) {
    __shared__ float ps[32][68];
    __shared__ float vs[32][68];
    const int blk = blockIdx.x;
    const int bh  = blk >> 3;
    const int nt  = blk & 7;
    const int b = bh / HH, h = bh % HH;
    const int tid = threadIdx.x;
    const int tx = tid & 15, ty = tid >> 4;
    const float* pb = attn + ((size_t)bh*NN + nt*64) * NN;
    const float* vb = v + (size_t)bh*NN*HD;
    float acc[4][4] = {};
    for (int k0 = 0; k0 < NN; k0 += 32) {
        const int pr = tid >> 3;
        const int pc = (tid & 7) * 4;
        float4 p0 = *(const float4*)(pb + (size_t)pr*NN + k0 + pc);
        float4 p1 = *(const float4*)(pb + (size_t)(pr + 32)*NN + k0 + pc);
        const int vr = tid >> 4;
        const int vc = (tid & 15) * 4;
        float4 v0 = *(const float4*)(vb + (size_t)(k0 + vr)*HD + vc);
        float4 v1 = *(const float4*)(vb + (size_t)(k0 + vr + 16)*HD + vc);
        __syncthreads();
        ps[pc+0][pr] = p0.x; ps[pc+1][pr] = p0.y; ps[pc+2][pr] = p0.z; ps[pc+3][pr] = p0.w;
        ps[pc+0][pr+32] = p1.x; ps[pc+1][pr+32] = p1.y; ps[pc+2][pr+32] = p1.z; ps[pc+3][pr+32] = p1.w;
        *(float4*)&vs[vr][vc]      = v0;
        *(float4*)&vs[vr+16][vc]   = v1;
        __syncthreads();
#pragma unroll
        for (int k = 0; k < 32; ++k) {
            float4 a4 = *(const float4*)&ps[k][ty*4];
            float4 b4 = *(const float4*)&vs[k][tx*4];
            float aa[4] = {a4.x, a4.y, a4.z, a4.w};
            float bb[4] = {b4.x, b4.y, b4.z, b4.w};
#pragma unroll
            for (int i = 0; i < 4; ++i)
#pragma unroll
                for (int j = 0; j < 4; ++j)
                    acc[i][j] += aa[i] * bb[j];
        }
    }
#pragma unroll
    for (int i = 0; i < 4; ++i) {
        int n = nt*64 + ty*4 + i;
        int mrow = b*NN + n;
        int c = h*HD + tx*4;
        ushort4 hi, lo;
        hi.x = f2bf(acc[i][0]); lo.x = f2bf(acc[i][0] - bf2f(hi.x));
        hi.y = f2bf(acc[i][1]); lo.y = f2bf(acc[i][1] - bf2f(hi.y));
        hi.z = f2bf(acc[i][2]); lo.z = f2bf(acc[i][2] - bf2f(hi.z));
        hi.w = f2bf(acc[i][3]); lo.w = f2bf(acc[i][3] - bf2f(hi.w));
        unsigned short* base = Ao + (size_t)mrow*KC + c;
        *(ushort4*)(base)        = hi;
        *(ushort4*)(base + CC)   = hi;
        *(ushort4*)(base + 2*CC) = lo;
    }
}

// ---------------------------------------------------------------------------
extern "C" void kernel_launch(void* const* d_in, const int* in_sizes, int n_in,
                              void* d_out, int out_size, void* d_ws, size_t ws_size,
                              hipStream_t stream) {
    const float* x      = (const float*)d_in[0];
    const float* qkv_w  = (const float*)d_in[1];
    const float* proj_w = (const float*)d_in[2];
    const float* proj_b = (const float*)d_in[3];
    const int*   islast = (const int*)d_in[4];

    float* out  = (float*)d_out;                       // [B,N,C]
    float* attn = out + (size_t)BB*NN*CC;              // [B,H,N,N]

    float* ws = (float*)d_ws;
    float* q  = ws;                                    // [B,H,N,hd] x3 contiguous
    float* k  = ws + (size_t)QKV_ELEMS;
    float* v  = ws + 2*(size_t)QKV_ELEMS;
    unsigned short* Asp   = (unsigned short*)(ws + 3*(size_t)QKV_ELEMS); // [4096][2304] (x-split, then o-split)
    unsigned short* Bqkv  = Asp  + (size_t)4096*KC;    // [2304][2304]
    unsigned short* Bproj = Bqkv + (size_t)2304*KC;    // [768][2304]

    split_k<true> <<<dim3(4096*CC/4/256), 256, 0, stream>>>(x,      Asp,   4096*CC/4);
    split_k<false><<<dim3(2304*CC/4/256), 256, 0, stream>>>(qkv_w,  Bqkv,  2304*CC/4);
    split_k<false><<<dim3(CC*CC/4/256),   256, 0, stream>>>(proj_w, Bproj, CC*CC/4);

    gemm_split<0, true>  <<<dim3(32, 18), 256, 0, stream>>>(Asp, Bqkv, nullptr, q);
    attn_scores_k        <<<dim3(96*32),  256, 0, stream>>>(q, k, islast, attn);
    attn_pv_k            <<<dim3(96*8),   256, 0, stream>>>(attn, v, Asp);
    gemm_split<CC, false><<<dim3(32, 6),  256, 0, stream>>>(Asp, Bproj, proj_b, out);
}